// Round 1
// baseline (233.785 us; speedup 1.0000x reference)
//
#include <hip/hip_runtime.h>

#define NL 48
#define NB 16
#define NC 128
#define NE 128
#define NROWS (NL*NL*NB)   // 36864

// ---- workspace layout (in floats) ----
#define H_N      (NROWS*NC)          // 4718592
#define VEC_N    (NL*NB*NC)          // 98304
#define RA_OFF   (H_N + 0*VEC_N)     // row_agg
#define CA_OFF   (H_N + 1*VEC_N)     // col_agg
#define DG_OFF   (H_N + 2*VEC_N)     // diag
#define AJ_OFF   (H_N + 3*VEC_N)     // j-dependent additive vector
#define AI_OFF   (H_N + 4*VEC_N)     // i-dependent additive vector
#define AD_OFF   (H_N + 5*VEC_N)     // diagonal-only additive vector
#define DGA_OFF  (H_N + 6*VEC_N)     // diag_agg [16,128]
#define AA_OFF   (DGA_OFF + NB*NC)   // all_agg [16,128]
#define AB_OFF   (AA_OFF + NB*NC)    // Abase   [16,128]
#define FLAG_OFF (AB_OFF + NB*NC)    // int flag (mask byte-stride)

__device__ __forceinline__ float silu_f(float x) {
  return x / (1.0f + __expf(-x));
}
// XOR swizzle for transposed LDS tiles [128 k][64 r], pad 68:
// keeps 4-row quads contiguous (b128-readable), kills the 8-way write conflict.
__device__ __forceinline__ int swz(int c, int r) {
  return c*68 + (r ^ (((c>>3)&7)<<3));
}

// ---------- kernel 0: detect mask dtype (bool bytes vs int32) ----------
__global__ void k_detect(const unsigned char* __restrict__ mb, int* __restrict__ flag) {
  __shared__ int any;
  if (threadIdx.x == 0) any = 0;
  __syncthreads();
  int acc = 0;
  for (int i = threadIdx.x; i < NL*NL*NB; i += blockDim.x)
    if (i & 3) acc |= mb[i];           // safe for both layouts (<= 36864 bytes)
  if (acc) atomicOr(&any, 1);
  __syncthreads();
  if (threadIdx.x == 0) *flag = any ? 1 : 4;   // byte stride between mask elements
}

// ---------- kernel A: H = silu(BN(T) @ w1 + b1) ----------
__global__ __launch_bounds__(256) void kA(const float* __restrict__ T,
    const float* __restrict__ rmean, const float* __restrict__ rvar,
    const float* __restrict__ bw, const float* __restrict__ bb,
    const float* __restrict__ w1, const float* __restrict__ b1,
    float* __restrict__ H)
{
  __shared__ float XT[128*68];     // transposed BN'd input tile [k][r]
  __shared__ float sc[128], sh[128];
  int tid = threadIdx.x;
  if (tid < 128) {
    float s = bw[tid] * rsqrtf(rvar[tid] + 1e-5f);
    sc[tid] = s; sh[tid] = bb[tid] - rmean[tid] * s;
  }
  __syncthreads();
  int m0 = blockIdx.x * 64;
  #pragma unroll
  for (int t = 0; t < 32; ++t) {
    int f = t*256 + tid;
    int r = f >> 7, c = f & 127;
    float v = T[m0*128 + f] * sc[c] + sh[c];
    XT[swz(c, r)] = v;
  }
  __syncthreads();
  int rg = tid >> 4, cg = tid & 15;
  float acc[4][8];
  #pragma unroll
  for (int cc = 0; cc < 4; ++cc) {
    float bva = b1[4*cg + cc], bvb = b1[64 + 4*cg + cc];
    #pragma unroll
    for (int rr = 0; rr < 4; ++rr) { acc[rr][cc] = bva; acc[rr][cc+4] = bvb; }
  }
  #pragma unroll 4
  for (int k = 0; k < 128; ++k) {
    int rb = (4*rg) ^ (((k>>3)&7)<<3);
    float4 xv = *(const float4*)&XT[k*68 + rb];
    float4 wa = *(const float4*)&w1[k*128 + 4*cg];
    float4 wb = *(const float4*)&w1[k*128 + 64 + 4*cg];
    float xr[4] = {xv.x, xv.y, xv.z, xv.w};
    float wc[8] = {wa.x,wa.y,wa.z,wa.w, wb.x,wb.y,wb.z,wb.w};
    #pragma unroll
    for (int rr = 0; rr < 4; ++rr)
      #pragma unroll
      for (int cc = 0; cc < 8; ++cc)
        acc[rr][cc] += xr[rr] * wc[cc];
  }
  #pragma unroll
  for (int rr = 0; rr < 4; ++rr) {
    int row = m0 + 4*rg + rr;
    float4 o0, o1;
    o0.x = silu_f(acc[rr][0]); o0.y = silu_f(acc[rr][1]);
    o0.z = silu_f(acc[rr][2]); o0.w = silu_f(acc[rr][3]);
    o1.x = silu_f(acc[rr][4]); o1.y = silu_f(acc[rr][5]);
    o1.z = silu_f(acc[rr][6]); o1.w = silu_f(acc[rr][7]);
    *(float4*)&H[row*128 + 4*cg]      = o0;
    *(float4*)&H[row*128 + 64 + 4*cg] = o1;
  }
}

// ---------- kernel B: row_agg / col_agg / diag ----------
__global__ __launch_bounds__(128) void kB(const float* __restrict__ H,
    const unsigned char* __restrict__ mb, const int* __restrict__ flag,
    float* __restrict__ row_agg, float* __restrict__ col_agg, float* __restrict__ diagv)
{
  int p = blockIdx.x, b = blockIdx.y, e = threadIdx.x;
  int s = *flag;
  float ac = 0.f, ar = 0.f;
  for (int q = 0; q < NL; ++q) {
    if (mb[((p*NL + q)*NB + b)*s]) ac += H[((p*NL + q)*NB + b)*128 + e]; // sum over j
    if (mb[((q*NL + p)*NB + b)*s]) ar += H[((q*NL + p)*NB + b)*128 + e]; // sum over i
  }
  int ix = (p*NB + b)*128 + e;
  col_agg[ix] = ac * (1.0f/60.0f);
  row_agg[ix] = ar * (1.0f/60.0f);
  diagv[ix]   = H[((p*NL + p)*NB + b)*128 + e];
}

// ---------- kernel C: all_agg, diag_agg, Abase ----------
__global__ __launch_bounds__(128) void kC(const float* __restrict__ H,
    const unsigned char* __restrict__ mb, const int* __restrict__ flag,
    const float* __restrict__ row_agg, const float* __restrict__ w2,
    const float* __restrict__ b2,
    float* __restrict__ diag_agg, float* __restrict__ all_agg, float* __restrict__ Abase)
{
  int b = blockIdx.x, e = threadIdx.x;
  int s = *flag;
  float aa = 0.f, dg = 0.f;
  for (int q = 0; q < NL; ++q) {
    aa += row_agg[(q*NB + b)*128 + e];
    if (mb[((q*NL + q)*NB + b)*s]) dg += H[((q*NL + q)*NB + b)*128 + e];
  }
  aa *= (1.0f/60.0f);   // -> sum(Hm)/3600
  dg *= (1.0f/60.0f);
  all_agg[b*128 + e] = aa;
  diag_agg[b*128 + e] = dg;
  __shared__ float aas[128], dgs[128];
  aas[e] = aa; dgs[e] = dg;
  __syncthreads();
  int c = e;
  float ab = b2[c];
  for (int k = 0; k < 128; ++k) {
    int o = k*128 + c;
    ab += dgs[k]*w2[8*16384 + o] + aas[k]*(w2[11*16384 + o] + w2[14*16384 + o]);
  }
  Abase[b*128 + c] = ab;
}

// ---------- kernel D: Aj / Ai / Adiag small GEMMs ----------
__global__ __launch_bounds__(128) void kD(const float* __restrict__ diagv,
    const float* __restrict__ row_agg, const float* __restrict__ col_agg,
    const float* __restrict__ diag_agg, const float* __restrict__ w2,
    float* __restrict__ Aj, float* __restrict__ Ai, float* __restrict__ Adg)
{
  int p = blockIdx.x, b = blockIdx.y, c = threadIdx.x;
  __shared__ float d[128], ra[128], ca[128], ga[128];
  int base = (p*NB + b)*128;
  d[c]  = diagv[base + c];
  ra[c] = row_agg[base + c];
  ca[c] = col_agg[base + c];
  ga[c] = diag_agg[b*128 + c];
  __syncthreads();
  float aj = 0.f, ai = 0.f, ad = 0.f;
  for (int e = 0; e < 128; ++e) {
    float de = d[e], re = ra[e], ce = ca[e], ge = ga[e];
    int o = e*128 + c;
    aj += de*w2[ 1*16384 + o] + re*w2[ 9*16384 + o] + ce*w2[10*16384 + o];
    ai += de*w2[ 2*16384 + o] + ce*w2[12*16384 + o] + re*w2[13*16384 + o];
    ad += de*w2[ 0*16384 + o] + re*w2[ 5*16384 + o] + ce*w2[ 6*16384 + o] + ge*w2[ 7*16384 + o];
  }
  Aj[base + c] = aj; Ai[base + c] = ai; Adg[base + c] = ad;
}

// ---------- kernel E: out = H@W4 + H^T@W3 + Aj + Ai + Abase + diag(Adg) ----------
__global__ __launch_bounds__(256) void kE(const float* __restrict__ H,
    const float* __restrict__ w2,
    const float* __restrict__ Aj, const float* __restrict__ Ai,
    const float* __restrict__ Adg, const float* __restrict__ Ab,
    float* __restrict__ out)
{
  __shared__ float HdT[128*68];
  __shared__ float HtT[128*68];
  int tid = threadIdx.x;
  int bi = blockIdx.x / 12;          // i (fixed for block)
  int j0 = (blockIdx.x % 12) * 4;    // 4 consecutive j
  int m0 = (bi*NL + j0) * NB;        // 64 consecutive rows
  #pragma unroll
  for (int t = 0; t < 32; ++t) {
    int f = t*256 + tid;
    int r = f >> 7, c = f & 127;
    int sw = swz(c, r);
    HdT[sw] = H[m0*128 + f];
    int j = j0 + (r >> 4), b = r & 15;
    HtT[sw] = H[((j*NL + bi)*NB + b)*128 + c];
  }
  __syncthreads();
  int rg = tid >> 4, cg = tid & 15;
  float acc[4][8];
  #pragma unroll
  for (int rr = 0; rr < 4; ++rr)
    #pragma unroll
    for (int cc = 0; cc < 8; ++cc) acc[rr][cc] = 0.f;

  const float* W3 = w2 + 3*16384;    // multiplies H[j,i]
  const float* W4 = w2 + 4*16384;    // multiplies H[i,j]
  #pragma unroll 2
  for (int k = 0; k < 128; ++k) {
    int rb = (4*rg) ^ (((k>>3)&7)<<3);
    float4 xd = *(const float4*)&HdT[k*68 + rb];
    float4 xt = *(const float4*)&HtT[k*68 + rb];
    float4 w4a = *(const float4*)&W4[k*128 + 4*cg];
    float4 w4b = *(const float4*)&W4[k*128 + 64 + 4*cg];
    float4 w3a = *(const float4*)&W3[k*128 + 4*cg];
    float4 w3b = *(const float4*)&W3[k*128 + 64 + 4*cg];
    float xdv[4] = {xd.x, xd.y, xd.z, xd.w};
    float xtv[4] = {xt.x, xt.y, xt.z, xt.w};
    float w4v[8] = {w4a.x,w4a.y,w4a.z,w4a.w, w4b.x,w4b.y,w4b.z,w4b.w};
    float w3v[8] = {w3a.x,w3a.y,w3a.z,w3a.w, w3b.x,w3b.y,w3b.z,w3b.w};
    #pragma unroll
    for (int rr = 0; rr < 4; ++rr)
      #pragma unroll
      for (int cc = 0; cc < 8; ++cc)
        acc[rr][cc] += xdv[rr]*w4v[cc] + xtv[rr]*w3v[cc];
  }
  #pragma unroll
  for (int rr = 0; rr < 4; ++rr) {
    int r = 4*rg + rr;
    int j = j0 + (r >> 4), b = r & 15;
    int m = m0 + r;
    int cb0 = 4*cg, cb1 = 64 + 4*cg;
    float4 aj0 = *(const float4*)&Aj[(j*NB + b)*128 + cb0];
    float4 aj1 = *(const float4*)&Aj[(j*NB + b)*128 + cb1];
    float4 ai0 = *(const float4*)&Ai[(bi*NB + b)*128 + cb0];
    float4 ai1 = *(const float4*)&Ai[(bi*NB + b)*128 + cb1];
    float4 ab0 = *(const float4*)&Ab[b*128 + cb0];
    float4 ab1 = *(const float4*)&Ab[b*128 + cb1];
    float4 r0, r1;
    r0.x = acc[rr][0] + aj0.x + ai0.x + ab0.x;
    r0.y = acc[rr][1] + aj0.y + ai0.y + ab0.y;
    r0.z = acc[rr][2] + aj0.z + ai0.z + ab0.z;
    r0.w = acc[rr][3] + aj0.w + ai0.w + ab0.w;
    r1.x = acc[rr][4] + aj1.x + ai1.x + ab1.x;
    r1.y = acc[rr][5] + aj1.y + ai1.y + ab1.y;
    r1.z = acc[rr][6] + aj1.z + ai1.z + ab1.z;
    r1.w = acc[rr][7] + aj1.w + ai1.w + ab1.w;
    if (bi == j) {
      float4 ad0 = *(const float4*)&Adg[(bi*NB + b)*128 + cb0];
      float4 ad1 = *(const float4*)&Adg[(bi*NB + b)*128 + cb1];
      r0.x += ad0.x; r0.y += ad0.y; r0.z += ad0.z; r0.w += ad0.w;
      r1.x += ad1.x; r1.y += ad1.y; r1.z += ad1.z; r1.w += ad1.w;
    }
    *(float4*)&out[m*128 + cb0] = r0;
    *(float4*)&out[m*128 + cb1] = r1;
  }
}

extern "C" void kernel_launch(void* const* d_in, const int* in_sizes, int n_in,
                              void* d_out, int out_size, void* d_ws, size_t ws_size,
                              hipStream_t stream) {
  (void)in_sizes; (void)n_in; (void)out_size; (void)ws_size;
  const float* T      = (const float*)d_in[0];
  const unsigned char* mask = (const unsigned char*)d_in[1];
  const float* rmean  = (const float*)d_in[2];
  const float* rvar   = (const float*)d_in[3];
  const float* bw     = (const float*)d_in[4];
  const float* bb     = (const float*)d_in[5];
  const float* w1     = (const float*)d_in[6];
  const float* b1     = (const float*)d_in[7];
  const float* w2     = (const float*)d_in[8];
  const float* b2     = (const float*)d_in[9];
  float* ws  = (float*)d_ws;
  float* out = (float*)d_out;

  float* H    = ws;
  float* ra   = ws + RA_OFF;
  float* ca   = ws + CA_OFF;
  float* dgv  = ws + DG_OFF;
  float* Aj   = ws + AJ_OFF;
  float* Ai   = ws + AI_OFF;
  float* Adg  = ws + AD_OFF;
  float* dga  = ws + DGA_OFF;
  float* aa   = ws + AA_OFF;
  float* Ab   = ws + AB_OFF;
  int*   flag = (int*)(ws + FLAG_OFF);

  k_detect<<<1, 256, 0, stream>>>(mask, flag);
  kA<<<NROWS/64, 256, 0, stream>>>(T, rmean, rvar, bw, bb, w1, b1, H);
  kB<<<dim3(NL, NB), 128, 0, stream>>>(H, mask, flag, ra, ca, dgv);
  kC<<<NB, 128, 0, stream>>>(H, mask, flag, ra, w2, b2, dga, aa, Ab);
  kD<<<dim3(NL, NB), 128, 0, stream>>>(dgv, ra, ca, dga, w2, Aj, Ai, Adg);
  kE<<<NROWS/64, 256, 0, stream>>>(H, w2, Aj, Ai, Adg, Ab, out);
}

// Round 2
// 181.241 us; speedup vs baseline: 1.2899x; 1.2899x over previous
//
#include <hip/hip_runtime.h>

typedef __attribute__((ext_vector_type(8))) short short8;
typedef __attribute__((ext_vector_type(4))) float f32x4;
typedef __attribute__((ext_vector_type(4))) unsigned short ushort4_t;

#define NL 48
#define NB 16
#define NROWS (NL*NL*NB)   // 36864

// ---- workspace layout (float units) ----
#define HB_N     (NROWS*128/2)            // bf16 H as float-slots: 2359296
#define HB_OFF   0
#define W1T_OFF  (HB_OFF + HB_N)          // bf16 [128n][128k] = 8192 floats
#define W34T_OFF (W1T_OFF + 8192)         // bf16 [128n][256k] = 16384 floats
#define VEC_N    (NL*NB*128)              // 98304
#define RA_OFF   (W34T_OFF + 16384)
#define CA_OFF   (RA_OFF + VEC_N)
#define DG_OFF   (CA_OFF + VEC_N)
#define AJ_OFF   (DG_OFF + VEC_N)
#define AI_OFF   (AJ_OFF + VEC_N)
#define AD_OFF   (AI_OFF + VEC_N)
#define DGA_OFF  (AD_OFF + VEC_N)
#define AA_OFF   (DGA_OFF + NB*128)
#define AB_OFF   (AA_OFF + NB*128)
#define FLAG_OFF (AB_OFF + NB*128)

__device__ __forceinline__ float silu_f(float x) { return x / (1.0f + __expf(-x)); }
__device__ __forceinline__ unsigned short f2bf(float x) {
  union { float f; unsigned u; } v; v.f = x;
  unsigned r = v.u + 0x7fffu + ((v.u >> 16) & 1u);
  return (unsigned short)(r >> 16);
}
__device__ __forceinline__ float bf2f(unsigned short h) {
  union { unsigned u; float f; } v; v.u = ((unsigned)h) << 16; return v.f;
}

// ---------- kernel 0: detect mask dtype (bool bytes vs int32) ----------
__global__ void k_detect(const unsigned char* __restrict__ mb, int* __restrict__ flag) {
  __shared__ int any;
  if (threadIdx.x == 0) any = 0;
  __syncthreads();
  int acc = 0;
  for (int i = threadIdx.x; i < NL*NL*NB; i += blockDim.x)
    if (i & 3) acc |= mb[i];
  if (acc) atomicOr(&any, 1);
  __syncthreads();
  if (threadIdx.x == 0) *flag = any ? 1 : 4;
}

// ---------- one-time weight transposes (fp32 -> bf16, [k][n] -> [n][k]) ----------
__global__ __launch_bounds__(256) void kW1t(const float* __restrict__ w1,
                                            unsigned short* __restrict__ w1t) {
  __shared__ float t[64*65];
  int k0 = blockIdx.x*64, n0 = blockIdx.y*64, tid = threadIdx.x;
  #pragma unroll
  for (int it = 0; it < 16; ++it) {
    int f = it*256 + tid; int kk = f>>6, nn = f&63;
    t[kk*65 + nn] = w1[(k0+kk)*128 + n0+nn];
  }
  __syncthreads();
  #pragma unroll
  for (int it = 0; it < 16; ++it) {
    int f = it*256 + tid; int nn = f>>6, kk = f&63;
    w1t[(n0+nn)*128 + k0+kk] = f2bf(t[kk*65 + nn]);
  }
}
// W34T[n][k] : k<128 -> w2 slice4 (pairs H[i,j]); k>=128 -> slice3 (pairs H[j,i])
__global__ __launch_bounds__(256) void kW34t(const float* __restrict__ w2,
                                             unsigned short* __restrict__ w34t) {
  __shared__ float t[64*65];
  int k0 = blockIdx.x*64, n0 = blockIdx.y*64, tid = threadIdx.x;
  #pragma unroll
  for (int it = 0; it < 16; ++it) {
    int f = it*256 + tid; int kk = f>>6, nn = f&63;
    int k = k0 + kk; int slice = (k < 128) ? 4 : 3;
    t[kk*65 + nn] = w2[slice*16384 + (k & 127)*128 + n0+nn];
  }
  __syncthreads();
  #pragma unroll
  for (int it = 0; it < 16; ++it) {
    int f = it*256 + tid; int nn = f>>6, kk = f&63;
    w34t[(n0+nn)*256 + k0+kk] = f2bf(t[kk*65 + nn]);
  }
}

// ---------- kernel A (MFMA): Hb = bf16(silu(BN(T) @ w1 + b1)) ----------
__global__ __launch_bounds__(256) void kA(const float* __restrict__ T,
    const float* __restrict__ rmean, const float* __restrict__ rvar,
    const float* __restrict__ bw, const float* __restrict__ bb,
    const unsigned short* __restrict__ w1t, const float* __restrict__ b1,
    unsigned short* __restrict__ Hb)
{
  __shared__ __align__(16) char XDS[64*256];    // [64 r][128 k] bf16, XOR-swizzled
  __shared__ __align__(16) char WDS[128*256];   // [128 n][128 k] bf16, XOR-swizzled
  int tid = threadIdx.x;
  int m0 = blockIdx.x * 64;

  // per-thread BN constants for its 4 fixed columns
  int cbase = (tid & 31) * 4;
  float scr[4], shr[4];
  #pragma unroll
  for (int u = 0; u < 4; ++u) {
    float s = bw[cbase+u] * rsqrtf(rvar[cbase+u] + 1e-5f);
    scr[u] = s; shr[u] = bb[cbase+u] - rmean[cbase+u] * s;
  }
  // stage X (BN + bf16), 64 rows x 32 float4-chunks
  #pragma unroll
  for (int t = 0; t < 8; ++t) {
    int f = t*256 + tid;
    int r = f >> 5, c4 = f & 31;
    float4 v = *(const float4*)&T[(m0 + r)*128 + c4*4];
    ushort4_t p;
    p.x = f2bf(v.x*scr[0] + shr[0]); p.y = f2bf(v.y*scr[1] + shr[1]);
    p.z = f2bf(v.z*scr[2] + shr[2]); p.w = f2bf(v.w*scr[3] + shr[3]);
    *(ushort4_t*)(XDS + r*256 + ((c4*8) ^ ((r & 7) << 4))) = p;
  }
  // stage W1T, 128 rows x 16 chunks16
  #pragma unroll
  for (int t = 0; t < 8; ++t) {
    int f = t*256 + tid;
    int r = f >> 4, c16 = f & 15;
    short8 v = *(const short8*)(w1t + r*128 + c16*8);
    *(short8*)(WDS + r*256 + ((c16*16) ^ ((r & 7) << 4))) = v;
  }
  __syncthreads();

  int wave = tid >> 6, lane = tid & 63;
  int ln = lane & 15, lg = lane >> 4;
  int rw = (wave >> 1) * 32, cw = (wave & 1) * 64;
  int swz = (ln & 7) << 4;
  f32x4 acc[2][4];
  #pragma unroll
  for (int mt = 0; mt < 2; ++mt)
    #pragma unroll
    for (int nt = 0; nt < 4; ++nt) acc[mt][nt] = (f32x4){0.f,0.f,0.f,0.f};

  #pragma unroll
  for (int ks = 0; ks < 4; ++ks) {
    int kb = ks*64 + lg*16;
    short8 a[2], b[4];
    #pragma unroll
    for (int mt = 0; mt < 2; ++mt)
      a[mt] = *(const short8*)(XDS + (rw + mt*16 + ln)*256 + (kb ^ swz));
    #pragma unroll
    for (int nt = 0; nt < 4; ++nt)
      b[nt] = *(const short8*)(WDS + (cw + nt*16 + ln)*256 + (kb ^ swz));
    #pragma unroll
    for (int mt = 0; mt < 2; ++mt)
      #pragma unroll
      for (int nt = 0; nt < 4; ++nt)
        acc[mt][nt] = __builtin_amdgcn_mfma_f32_16x16x32_bf16(a[mt], b[nt], acc[mt][nt], 0, 0, 0);
  }
  // epilogue: +b1, silu, bf16 store
  float b1v[4];
  #pragma unroll
  for (int nt = 0; nt < 4; ++nt) b1v[nt] = b1[cw + nt*16 + ln];
  #pragma unroll
  for (int mt = 0; mt < 2; ++mt)
    #pragma unroll
    for (int q = 0; q < 4; ++q) {
      int m = m0 + rw + mt*16 + 4*lg + q;
      #pragma unroll
      for (int nt = 0; nt < 4; ++nt) {
        float x = acc[mt][nt][q] + b1v[nt];
        Hb[m*128 + cw + nt*16 + ln] = f2bf(silu_f(x));
      }
    }
}

// ---------- kernel B: row_agg / col_agg / diag (bf16 H) ----------
__global__ __launch_bounds__(128) void kB(const unsigned short* __restrict__ Hb,
    const unsigned char* __restrict__ mb, const int* __restrict__ flag,
    float* __restrict__ row_agg, float* __restrict__ col_agg, float* __restrict__ diagv)
{
  int p = blockIdx.x, b = blockIdx.y, e = threadIdx.x;
  int s = *flag;
  float ac = 0.f, ar = 0.f;
  for (int q = 0; q < NL; ++q) {
    if (mb[((p*NL + q)*NB + b)*s]) ac += bf2f(Hb[((p*NL + q)*NB + b)*128 + e]);
    if (mb[((q*NL + p)*NB + b)*s]) ar += bf2f(Hb[((q*NL + p)*NB + b)*128 + e]);
  }
  int ix = (p*NB + b)*128 + e;
  col_agg[ix] = ac * (1.0f/60.0f);
  row_agg[ix] = ar * (1.0f/60.0f);
  diagv[ix]   = bf2f(Hb[((p*NL + p)*NB + b)*128 + e]);
}

// ---------- kernel C: all_agg, diag_agg, Abase ----------
__global__ __launch_bounds__(128) void kC(const unsigned short* __restrict__ Hb,
    const unsigned char* __restrict__ mb, const int* __restrict__ flag,
    const float* __restrict__ row_agg, const float* __restrict__ w2,
    const float* __restrict__ b2,
    float* __restrict__ diag_agg, float* __restrict__ all_agg, float* __restrict__ Abase)
{
  int b = blockIdx.x, e = threadIdx.x;
  int s = *flag;
  float aa = 0.f, dg = 0.f;
  for (int q = 0; q < NL; ++q) {
    aa += row_agg[(q*NB + b)*128 + e];
    if (mb[((q*NL + q)*NB + b)*s]) dg += bf2f(Hb[((q*NL + q)*NB + b)*128 + e]);
  }
  aa *= (1.0f/60.0f);
  dg *= (1.0f/60.0f);
  all_agg[b*128 + e] = aa;
  diag_agg[b*128 + e] = dg;
  __shared__ float aas[128], dgs[128];
  aas[e] = aa; dgs[e] = dg;
  __syncthreads();
  int c = e;
  float ab = b2[c];
  for (int k = 0; k < 128; ++k) {
    int o = k*128 + c;
    ab += dgs[k]*w2[8*16384 + o] + aas[k]*(w2[11*16384 + o] + w2[14*16384 + o]);
  }
  Abase[b*128 + c] = ab;
}

// ---------- kernel D: Aj / Ai / Adiag small GEMMs ----------
__global__ __launch_bounds__(128) void kD(const float* __restrict__ diagv,
    const float* __restrict__ row_agg, const float* __restrict__ col_agg,
    const float* __restrict__ diag_agg, const float* __restrict__ w2,
    float* __restrict__ Aj, float* __restrict__ Ai, float* __restrict__ Adg)
{
  int p = blockIdx.x, b = blockIdx.y, c = threadIdx.x;
  __shared__ float d[128], ra[128], ca[128], ga[128];
  int base = (p*NB + b)*128;
  d[c]  = diagv[base + c];
  ra[c] = row_agg[base + c];
  ca[c] = col_agg[base + c];
  ga[c] = diag_agg[b*128 + c];
  __syncthreads();
  float aj = 0.f, ai = 0.f, ad = 0.f;
  for (int e = 0; e < 128; ++e) {
    float de = d[e], re = ra[e], ce = ca[e], ge = ga[e];
    int o = e*128 + c;
    aj += de*w2[ 1*16384 + o] + re*w2[ 9*16384 + o] + ce*w2[10*16384 + o];
    ai += de*w2[ 2*16384 + o] + ce*w2[12*16384 + o] + re*w2[13*16384 + o];
    ad += de*w2[ 0*16384 + o] + re*w2[ 5*16384 + o] + ce*w2[ 6*16384 + o] + ge*w2[ 7*16384 + o];
  }
  Aj[base + c] = aj; Ai[base + c] = ai; Adg[base + c] = ad;
}

// ---------- kernel E (MFMA): out = [Hd|Ht] @ W34T^T + additive ----------
__global__ __launch_bounds__(256) void kE(const unsigned short* __restrict__ Hb,
    const unsigned short* __restrict__ w34t,
    const float* __restrict__ Aj, const float* __restrict__ Ai,
    const float* __restrict__ Adg, const float* __restrict__ Ab,
    float* __restrict__ out)
{
  __shared__ __align__(16) char ADS[64*512];    // [64 r][256 k] bf16, swizzled
  __shared__ __align__(16) char BDS[128*256];   // [128 n][128 k] bf16, swizzled (per half)
  int tid = threadIdx.x;
  int bi = blockIdx.x / 12;
  int j0 = (blockIdx.x % 12) * 4;

  // stage ADS: k<128 from H[i,j], k>=128 from H[j,i]
  #pragma unroll
  for (int t = 0; t < 8; ++t) {
    int f = t*256 + tid;
    int r = f >> 5, c16 = f & 31;
    int j = j0 + (r >> 4), b = r & 15;
    int srcrow = (c16 < 16) ? ((bi*NL + j)*NB + b) : ((j*NL + bi)*NB + b);
    short8 v = *(const short8*)(Hb + srcrow*128 + (c16 & 15)*8);
    *(short8*)(ADS + r*512 + ((c16*16) ^ ((r & 7) << 4))) = v;
  }

  int wave = tid >> 6, lane = tid & 63;
  int ln = lane & 15, lg = lane >> 4;
  int rw = (wave >> 1) * 32, cw = (wave & 1) * 64;
  int swz = (ln & 7) << 4;
  f32x4 acc[2][4];
  #pragma unroll
  for (int mt = 0; mt < 2; ++mt)
    #pragma unroll
    for (int nt = 0; nt < 4; ++nt) acc[mt][nt] = (f32x4){0.f,0.f,0.f,0.f};

  #pragma unroll
  for (int half = 0; half < 2; ++half) {
    __syncthreads();   // half0: ADS ready; half1: previous BDS consumed
    #pragma unroll
    for (int t = 0; t < 8; ++t) {
      int f = t*256 + tid;
      int r = f >> 4, c16 = f & 15;
      short8 v = *(const short8*)(w34t + r*256 + half*128 + c16*8);
      *(short8*)(BDS + r*256 + ((c16*16) ^ ((r & 7) << 4))) = v;
    }
    __syncthreads();
    #pragma unroll
    for (int ks = 0; ks < 4; ++ks) {
      int kbA = half*256 + ks*64 + lg*16;
      int kbB = ks*64 + lg*16;
      short8 a[2], b[4];
      #pragma unroll
      for (int mt = 0; mt < 2; ++mt)
        a[mt] = *(const short8*)(ADS + (rw + mt*16 + ln)*512 + (kbA ^ swz));
      #pragma unroll
      for (int nt = 0; nt < 4; ++nt)
        b[nt] = *(const short8*)(BDS + (cw + nt*16 + ln)*256 + (kbB ^ swz));
      #pragma unroll
      for (int mt = 0; mt < 2; ++mt)
        #pragma unroll
        for (int nt = 0; nt < 4; ++nt)
          acc[mt][nt] = __builtin_amdgcn_mfma_f32_16x16x32_bf16(a[mt], b[nt], acc[mt][nt], 0, 0, 0);
    }
  }

  // epilogue: additive low-rank terms + store f32
  #pragma unroll
  for (int mt = 0; mt < 2; ++mt) {
    int tb = rw + mt*16;
    int jj = tb >> 4;
    int j = j0 + jj;
    bool isdiag = (bi == j);
    #pragma unroll
    for (int q = 0; q < 4; ++q) {
      int b = 4*lg + q;
      int m = (bi*NL + j)*NB + b;
      #pragma unroll
      for (int nt = 0; nt < 4; ++nt) {
        int n = cw + nt*16 + ln;
        float add = Aj[(j*NB + b)*128 + n] + Ai[(bi*NB + b)*128 + n] + Ab[b*128 + n];
        if (isdiag) add += Adg[(bi*NB + b)*128 + n];
        out[m*128 + n] = acc[mt][nt][q] + add;
      }
    }
  }
}

extern "C" void kernel_launch(void* const* d_in, const int* in_sizes, int n_in,
                              void* d_out, int out_size, void* d_ws, size_t ws_size,
                              hipStream_t stream) {
  (void)in_sizes; (void)n_in; (void)out_size; (void)ws_size;
  const float* T      = (const float*)d_in[0];
  const unsigned char* mask = (const unsigned char*)d_in[1];
  const float* rmean  = (const float*)d_in[2];
  const float* rvar   = (const float*)d_in[3];
  const float* bw     = (const float*)d_in[4];
  const float* bb     = (const float*)d_in[5];
  const float* w1     = (const float*)d_in[6];
  const float* b1     = (const float*)d_in[7];
  const float* w2     = (const float*)d_in[8];
  const float* b2     = (const float*)d_in[9];
  float* ws  = (float*)d_ws;
  float* out = (float*)d_out;

  unsigned short* Hb   = (unsigned short*)(ws + HB_OFF);
  unsigned short* w1t  = (unsigned short*)(ws + W1T_OFF);
  unsigned short* w34t = (unsigned short*)(ws + W34T_OFF);
  float* ra   = ws + RA_OFF;
  float* ca   = ws + CA_OFF;
  float* dgv  = ws + DG_OFF;
  float* Aj   = ws + AJ_OFF;
  float* Ai   = ws + AI_OFF;
  float* Adg  = ws + AD_OFF;
  float* dga  = ws + DGA_OFF;
  float* aa   = ws + AA_OFF;
  float* Ab   = ws + AB_OFF;
  int*   flag = (int*)(ws + FLAG_OFF);

  k_detect<<<1, 256, 0, stream>>>(mask, flag);
  kW1t<<<dim3(2, 2), 256, 0, stream>>>(w1, w1t);
  kW34t<<<dim3(4, 2), 256, 0, stream>>>(w2, w34t);
  kA<<<NROWS/64, 256, 0, stream>>>(T, rmean, rvar, bw, bb, w1t, b1, Hb);
  kB<<<dim3(NL, NB), 128, 0, stream>>>(Hb, mask, flag, ra, ca, dgv);
  kC<<<NB, 128, 0, stream>>>(Hb, mask, flag, ra, w2, b2, dga, aa, Ab);
  kD<<<dim3(NL, NB), 128, 0, stream>>>(dgv, ra, ca, dga, w2, Aj, Ai, Adg);
  kE<<<NROWS/64, 256, 0, stream>>>(Hb, w34t, Aj, Ai, Adg, Ab, out);
}

// Round 4
// 112.749 us; speedup vs baseline: 2.0735x; 1.6075x over previous
//
#include <hip/hip_runtime.h>

typedef __attribute__((ext_vector_type(8))) short short8;
typedef __attribute__((ext_vector_type(4))) float f32x4;
typedef __attribute__((ext_vector_type(4))) unsigned short ushort4_t;

#define NL 48
#define NB 16
#define NROWS (NL*NL*NB)   // 36864

// ---- workspace layout (float units) ----
#define HB_N     (NROWS*128/2)            // bf16 H: 2359296 float-slots
#define HB_OFF   0
#define W1T_OFF  (HB_OFF + HB_N)          // bf16 [128n][128k] = 8192 floats
#define W34T_OFF (W1T_OFF + 8192)         // bf16 [128n][256k] = 16384 floats
#define WD_OFF   (W34T_OFF + 16384)       // bf16 [384n][512k] = 98304 floats
#define X2_OFF   (WD_OFF + 98304)         // bf16 [768m][512k] = 196608 floats
#define VEC_N    (NL*NB*128)              // 98304
#define RA_OFF   (X2_OFF + 196608)
#define CA_OFF   (RA_OFF + VEC_N)
#define AJ_OFF   (CA_OFF + VEC_N)
#define AI_OFF   (AJ_OFF + VEC_N)
#define AD_OFF   (AI_OFF + VEC_N)
#define AB_OFF   (AD_OFF + VEC_N)
#define FLAG_OFF (AB_OFF + NB*128)

__device__ __forceinline__ float silu_f(float x) { return x / (1.0f + __expf(-x)); }
__device__ __forceinline__ unsigned short f2bf(float x) {
  union { float f; unsigned u; } v; v.f = x;
  unsigned r = v.u + 0x7fffu + ((v.u >> 16) & 1u);
  return (unsigned short)(r >> 16);
}
__device__ __forceinline__ float bf2f(unsigned short h) {
  union { unsigned u; float f; } v; v.u = ((unsigned)h) << 16; return v.f;
}

// ---------- kPrep: weight transposes + Wd pack + mask-dtype detect, one launch ----------
// blocks 0-3: w1t; 4-11: w34t; 12-59: wd; 60: detect
__global__ __launch_bounds__(256) void kPrep(const float* __restrict__ w1,
    const float* __restrict__ w2, const unsigned char* __restrict__ mb,
    unsigned short* __restrict__ w1t, unsigned short* __restrict__ w34t,
    unsigned short* __restrict__ wd, int* __restrict__ flag)
{
  __shared__ float t[64*65];
  __shared__ int any;
  int blk = blockIdx.x, tid = threadIdx.x;
  if (blk < 4) {
    int k0 = (blk & 1)*64, n0 = (blk >> 1)*64;
    #pragma unroll
    for (int it = 0; it < 16; ++it) { int f = it*256+tid; int kk=f>>6, nn=f&63;
      t[kk*65+nn] = w1[(k0+kk)*128 + n0+nn]; }
    __syncthreads();
    #pragma unroll
    for (int it = 0; it < 16; ++it) { int f = it*256+tid; int nn=f>>6, kk=f&63;
      w1t[(n0+nn)*128 + k0+kk] = f2bf(t[kk*65+nn]); }
  } else if (blk < 12) {
    int q = blk-4; int k0 = (q&3)*64, n0 = (q>>2)*64;
    #pragma unroll
    for (int it = 0; it < 16; ++it) { int f = it*256+tid; int kk=f>>6, nn=f&63;
      int k = k0+kk; int slice = (k < 128) ? 4 : 3;
      t[kk*65+nn] = w2[slice*16384 + (k&127)*128 + n0+nn]; }
    __syncthreads();
    #pragma unroll
    for (int it = 0; it < 16; ++it) { int f = it*256+tid; int nn=f>>6, kk=f&63;
      w34t[(n0+nn)*256 + k0+kk] = f2bf(t[kk*65+nn]); }
  } else if (blk < 60) {
    int q = blk-12; int k0 = (q&7)*64, n0 = (q>>3)*64;
    int nq = n0 >> 7, kq = k0 >> 7;
    int slice;
    {
      const int sl_aj[4] = {1,9,10,-1};
      const int sl_ai[4] = {2,13,12,-1};
      const int sl_ad[4] = {0,5,6,7};
      slice = (nq==0) ? sl_aj[kq] : (nq==1) ? sl_ai[kq] : sl_ad[kq];
    }
    int nb = n0 & 127;
    #pragma unroll
    for (int it = 0; it < 16; ++it) { int f = it*256+tid; int kk=f>>6, nn=f&63;
      t[kk*65+nn] = (slice < 0) ? 0.f : w2[slice*16384 + ((k0&127)+kk)*128 + nb+nn]; }
    __syncthreads();
    #pragma unroll
    for (int it = 0; it < 16; ++it) { int f = it*256+tid; int nn=f>>6, kk=f&63;
      wd[(n0+nn)*512 + k0+kk] = f2bf(t[kk*65+nn]); }
  } else {
    if (tid == 0) any = 0;
    __syncthreads();
    int acc = 0;
    #pragma unroll
    for (int k2 = 0; k2 < 12; ++k2) {
      uchar4 v = ((const uchar4*)mb)[tid + k2*256];
      acc |= v.y | v.z | v.w;
    }
    if (acc) atomicOr(&any, 1);
    __syncthreads();
    if (tid == 0) *flag = any ? 1 : 4;
  }
}

// ---------- kernel A (MFMA): Hb = bf16(silu(BN(T) @ w1 + b1)) ----------
__global__ __launch_bounds__(256) void kA(const float* __restrict__ T,
    const float* __restrict__ rmean, const float* __restrict__ rvar,
    const float* __restrict__ bw, const float* __restrict__ bb,
    const unsigned short* __restrict__ w1t, const float* __restrict__ b1,
    unsigned short* __restrict__ Hb)
{
  __shared__ __align__(16) char XDS[64*256];    // [64 r][128 k] bf16, XOR-swizzled
  __shared__ __align__(16) char WDS[128*256];   // [128 n][128 k] bf16, XOR-swizzled
  int tid = threadIdx.x;
  int m0 = blockIdx.x * 64;

  int cbase = (tid & 31) * 4;
  float scr[4], shr[4];
  #pragma unroll
  for (int u = 0; u < 4; ++u) {
    float s = bw[cbase+u] * rsqrtf(rvar[cbase+u] + 1e-5f);
    scr[u] = s; shr[u] = bb[cbase+u] - rmean[cbase+u] * s;
  }
  #pragma unroll
  for (int t = 0; t < 8; ++t) {
    int f = t*256 + tid;
    int r = f >> 5, c4 = f & 31;
    float4 v = *(const float4*)&T[(m0 + r)*128 + c4*4];
    ushort4_t p;
    p.x = f2bf(v.x*scr[0] + shr[0]); p.y = f2bf(v.y*scr[1] + shr[1]);
    p.z = f2bf(v.z*scr[2] + shr[2]); p.w = f2bf(v.w*scr[3] + shr[3]);
    *(ushort4_t*)(XDS + r*256 + ((c4*8) ^ ((r & 7) << 4))) = p;
  }
  #pragma unroll
  for (int t = 0; t < 8; ++t) {
    int f = t*256 + tid;
    int r = f >> 4, c16 = f & 15;
    short8 v = *(const short8*)(w1t + r*128 + c16*8);
    *(short8*)(WDS + r*256 + ((c16*16) ^ ((r & 7) << 4))) = v;
  }
  __syncthreads();

  int wave = tid >> 6, lane = tid & 63;
  int ln = lane & 15, lg = lane >> 4;
  int rw = (wave >> 1) * 32, cw = (wave & 1) * 64;
  int swz = (ln & 7) << 4;
  f32x4 acc[2][4];
  #pragma unroll
  for (int mt = 0; mt < 2; ++mt)
    #pragma unroll
    for (int nt = 0; nt < 4; ++nt) acc[mt][nt] = (f32x4){0.f,0.f,0.f,0.f};

  #pragma unroll
  for (int ks = 0; ks < 4; ++ks) {
    int kb = ks*64 + lg*16;
    short8 a[2], b[4];
    #pragma unroll
    for (int mt = 0; mt < 2; ++mt)
      a[mt] = *(const short8*)(XDS + (rw + mt*16 + ln)*256 + (kb ^ swz));
    #pragma unroll
    for (int nt = 0; nt < 4; ++nt)
      b[nt] = *(const short8*)(WDS + (cw + nt*16 + ln)*256 + (kb ^ swz));
    #pragma unroll
    for (int mt = 0; mt < 2; ++mt)
      #pragma unroll
      for (int nt = 0; nt < 4; ++nt)
        acc[mt][nt] = __builtin_amdgcn_mfma_f32_16x16x32_bf16(a[mt], b[nt], acc[mt][nt], 0, 0, 0);
  }
  float b1v[4];
  #pragma unroll
  for (int nt = 0; nt < 4; ++nt) b1v[nt] = b1[cw + nt*16 + ln];
  #pragma unroll
  for (int mt = 0; mt < 2; ++mt)
    #pragma unroll
    for (int q = 0; q < 4; ++q) {
      int m = m0 + rw + mt*16 + 4*lg + q;
      #pragma unroll
      for (int nt = 0; nt < 4; ++nt) {
        float x = acc[mt][nt][q] + b1v[nt];
        Hb[m*128 + cw + nt*16 + ln] = f2bf(silu_f(x));
      }
    }
}

// ---------- kernel B: row_agg / col_agg (f32) + X2 quarters 0-2 (bf16) ----------
__global__ __launch_bounds__(128) void kB(const unsigned short* __restrict__ Hb,
    const unsigned char* __restrict__ mb, const int* __restrict__ flag,
    float* __restrict__ row_agg, float* __restrict__ col_agg,
    unsigned short* __restrict__ X2)
{
  int p = blockIdx.x, b = blockIdx.y, e = threadIdx.x;
  int s = *flag;
  float ac = 0.f, ar = 0.f;
  for (int q = 0; q < NL; ++q) {
    if (mb[((p*NL + q)*NB + b)*s]) ac += bf2f(Hb[((p*NL + q)*NB + b)*128 + e]);
    if (mb[((q*NL + p)*NB + b)*s]) ar += bf2f(Hb[((q*NL + p)*NB + b)*128 + e]);
  }
  ac *= (1.0f/60.0f); ar *= (1.0f/60.0f);
  int ix = p*NB + b;
  col_agg[ix*128 + e] = ac;
  row_agg[ix*128 + e] = ar;
  unsigned short dgb = Hb[((p*NL + p)*NB + b)*128 + e];   // already bf16
  X2[ix*512 + e]       = dgb;
  X2[ix*512 + 128 + e] = f2bf(ar);
  X2[ix*512 + 256 + e] = f2bf(ac);
}

// ---------- kernel C: Abase + X2 quarter 3 (diag_agg) ----------
__global__ __launch_bounds__(128) void kC(const unsigned short* __restrict__ Hb,
    const unsigned char* __restrict__ mb, const int* __restrict__ flag,
    const float* __restrict__ row_agg, const float* __restrict__ w2,
    const float* __restrict__ b2,
    unsigned short* __restrict__ X2, float* __restrict__ Abase)
{
  int b = blockIdx.x, e = threadIdx.x;
  int s = *flag;
  float aa = 0.f, dg = 0.f;
  for (int q = 0; q < NL; ++q) {
    aa += row_agg[(q*NB + b)*128 + e];
    if (mb[((q*NL + q)*NB + b)*s]) dg += bf2f(Hb[((q*NL + q)*NB + b)*128 + e]);
  }
  aa *= (1.0f/60.0f);
  dg *= (1.0f/60.0f);
  unsigned short gb = f2bf(dg);
  for (int p = 0; p < NL; ++p) X2[(p*NB + b)*512 + 384 + e] = gb;
  __shared__ float aas[128], dgs[128];
  aas[e] = aa; dgs[e] = dg;
  __syncthreads();
  int c = e;
  float ab = b2[c];
  for (int k = 0; k < 128; ++k) {
    int o = k*128 + c;
    ab += dgs[k]*w2[8*16384 + o] + aas[k]*(w2[11*16384 + o] + w2[14*16384 + o]);
  }
  Abase[b*128 + c] = ab;
}

// ---------- kernel Dm (MFMA): [Aj|Ai|Adg] = X2 @ Wd^T ----------
__global__ __launch_bounds__(256) void kDm(const unsigned short* __restrict__ X2,
    const unsigned short* __restrict__ wd,
    float* __restrict__ Aj, float* __restrict__ Ai, float* __restrict__ Adg)
{
  __shared__ __align__(16) char ADS[64*256];    // [64 r][128 k] per chunk
  __shared__ __align__(16) char BDS[128*256];   // [128 n][128 k] per chunk
  int tid = threadIdx.x;
  int m0 = blockIdx.x * 64;
  int n0 = blockIdx.y * 128;

  int wave = tid >> 6, lane = tid & 63;
  int ln = lane & 15, lg = lane >> 4;
  int rw = (wave >> 1) * 32, cw = (wave & 1) * 64;
  int swzk = (ln & 7) << 4;
  f32x4 acc[2][4];
  #pragma unroll
  for (int mt = 0; mt < 2; ++mt)
    #pragma unroll
    for (int nt = 0; nt < 4; ++nt) acc[mt][nt] = (f32x4){0.f,0.f,0.f,0.f};

  for (int kc = 0; kc < 4; ++kc) {
    if (kc) __syncthreads();
    #pragma unroll
    for (int t = 0; t < 4; ++t) {
      int f = t*256 + tid;
      int r = f >> 4, c16 = f & 15;
      short8 v = *(const short8*)(X2 + (m0 + r)*512 + kc*128 + c16*8);
      *(short8*)(ADS + r*256 + ((c16*16) ^ ((r & 7) << 4))) = v;
    }
    #pragma unroll
    for (int t = 0; t < 8; ++t) {
      int f = t*256 + tid;
      int r = f >> 4, c16 = f & 15;
      short8 v = *(const short8*)(wd + (n0 + r)*512 + kc*128 + c16*8);
      *(short8*)(BDS + r*256 + ((c16*16) ^ ((r & 7) << 4))) = v;
    }
    __syncthreads();
    // K=128 per chunk: 4 ks-steps of 32 (fragment spans 64 bytes per step)
    #pragma unroll
    for (int ks = 0; ks < 4; ++ks) {
      int kb = ks*64 + lg*16;
      short8 a[2], b[4];
      #pragma unroll
      for (int mt = 0; mt < 2; ++mt)
        a[mt] = *(const short8*)(ADS + (rw + mt*16 + ln)*256 + (kb ^ swzk));
      #pragma unroll
      for (int nt = 0; nt < 4; ++nt)
        b[nt] = *(const short8*)(BDS + (cw + nt*16 + ln)*256 + (kb ^ swzk));
      #pragma unroll
      for (int mt = 0; mt < 2; ++mt)
        #pragma unroll
        for (int nt = 0; nt < 4; ++nt)
          acc[mt][nt] = __builtin_amdgcn_mfma_f32_16x16x32_bf16(a[mt], b[nt], acc[mt][nt], 0, 0, 0);
    }
  }
  float* outp = (blockIdx.y == 0) ? Aj : (blockIdx.y == 1) ? Ai : Adg;
  #pragma unroll
  for (int mt = 0; mt < 2; ++mt)
    #pragma unroll
    for (int q = 0; q < 4; ++q) {
      int row = m0 + rw + mt*16 + 4*lg + q;
      #pragma unroll
      for (int nt = 0; nt < 4; ++nt)
        outp[row*128 + cw + nt*16 + ln] = acc[mt][nt][q];
    }
}

// ---------- kernel E (MFMA): out = [Hd|Ht] @ W34T^T + additive ----------
__global__ __launch_bounds__(256) void kE(const unsigned short* __restrict__ Hb,
    const unsigned short* __restrict__ w34t,
    const float* __restrict__ Aj, const float* __restrict__ Ai,
    const float* __restrict__ Adg, const float* __restrict__ Ab,
    float* __restrict__ out)
{
  __shared__ __align__(16) char ADS[64*512];
  __shared__ __align__(16) char BDS[128*256];
  int tid = threadIdx.x;
  int bi = blockIdx.x / 12;
  int j0 = (blockIdx.x % 12) * 4;

  #pragma unroll
  for (int t = 0; t < 8; ++t) {
    int f = t*256 + tid;
    int r = f >> 5, c16 = f & 31;
    int j = j0 + (r >> 4), b = r & 15;
    int srcrow = (c16 < 16) ? ((bi*NL + j)*NB + b) : ((j*NL + bi)*NB + b);
    short8 v = *(const short8*)(Hb + srcrow*128 + (c16 & 15)*8);
    *(short8*)(ADS + r*512 + ((c16*16) ^ ((r & 7) << 4))) = v;
  }

  int wave = tid >> 6, lane = tid & 63;
  int ln = lane & 15, lg = lane >> 4;
  int rw = (wave >> 1) * 32, cw = (wave & 1) * 64;
  int swz = (ln & 7) << 4;
  f32x4 acc[2][4];
  #pragma unroll
  for (int mt = 0; mt < 2; ++mt)
    #pragma unroll
    for (int nt = 0; nt < 4; ++nt) acc[mt][nt] = (f32x4){0.f,0.f,0.f,0.f};

  #pragma unroll
  for (int half = 0; half < 2; ++half) {
    __syncthreads();
    #pragma unroll
    for (int t = 0; t < 8; ++t) {
      int f = t*256 + tid;
      int r = f >> 4, c16 = f & 15;
      short8 v = *(const short8*)(w34t + r*256 + half*128 + c16*8);
      *(short8*)(BDS + r*256 + ((c16*16) ^ ((r & 7) << 4))) = v;
    }
    __syncthreads();
    #pragma unroll
    for (int ks = 0; ks < 4; ++ks) {
      int kbA = half*256 + ks*64 + lg*16;
      int kbB = ks*64 + lg*16;
      short8 a[2], b[4];
      #pragma unroll
      for (int mt = 0; mt < 2; ++mt)
        a[mt] = *(const short8*)(ADS + (rw + mt*16 + ln)*512 + (kbA ^ swz));
      #pragma unroll
      for (int nt = 0; nt < 4; ++nt)
        b[nt] = *(const short8*)(BDS + (cw + nt*16 + ln)*256 + (kbB ^ swz));
      #pragma unroll
      for (int mt = 0; mt < 2; ++mt)
        #pragma unroll
        for (int nt = 0; nt < 4; ++nt)
          acc[mt][nt] = __builtin_amdgcn_mfma_f32_16x16x32_bf16(a[mt], b[nt], acc[mt][nt], 0, 0, 0);
    }
  }

  #pragma unroll
  for (int mt = 0; mt < 2; ++mt) {
    int tb = rw + mt*16;
    int jj = tb >> 4;
    int j = j0 + jj;
    bool isdiag = (bi == j);
    #pragma unroll
    for (int q = 0; q < 4; ++q) {
      int b = 4*lg + q;
      int m = (bi*NL + j)*NB + b;
      #pragma unroll
      for (int nt = 0; nt < 4; ++nt) {
        int n = cw + nt*16 + ln;
        float add = Aj[(j*NB + b)*128 + n] + Ai[(bi*NB + b)*128 + n] + Ab[b*128 + n];
        if (isdiag) add += Adg[(bi*NB + b)*128 + n];
        out[m*128 + n] = acc[mt][nt][q] + add;
      }
    }
  }
}

extern "C" void kernel_launch(void* const* d_in, const int* in_sizes, int n_in,
                              void* d_out, int out_size, void* d_ws, size_t ws_size,
                              hipStream_t stream) {
  (void)in_sizes; (void)n_in; (void)out_size; (void)ws_size;
  const float* T      = (const float*)d_in[0];
  const unsigned char* mask = (const unsigned char*)d_in[1];
  const float* rmean  = (const float*)d_in[2];
  const float* rvar   = (const float*)d_in[3];
  const float* bw     = (const float*)d_in[4];
  const float* bb     = (const float*)d_in[5];
  const float* w1     = (const float*)d_in[6];
  const float* b1     = (const float*)d_in[7];
  const float* w2     = (const float*)d_in[8];
  const float* b2     = (const float*)d_in[9];
  float* ws  = (float*)d_ws;
  float* out = (float*)d_out;

  unsigned short* Hb   = (unsigned short*)(ws + HB_OFF);
  unsigned short* w1t  = (unsigned short*)(ws + W1T_OFF);
  unsigned short* w34t = (unsigned short*)(ws + W34T_OFF);
  unsigned short* wd   = (unsigned short*)(ws + WD_OFF);
  unsigned short* X2   = (unsigned short*)(ws + X2_OFF);
  float* ra   = ws + RA_OFF;
  float* ca   = ws + CA_OFF;
  float* Aj   = ws + AJ_OFF;
  float* Ai   = ws + AI_OFF;
  float* Adg  = ws + AD_OFF;
  float* Ab   = ws + AB_OFF;
  int*   flag = (int*)(ws + FLAG_OFF);

  kPrep<<<61, 256, 0, stream>>>(w1, w2, mask, w1t, w34t, wd, flag);
  kA<<<NROWS/64, 256, 0, stream>>>(T, rmean, rvar, bw, bb, w1t, b1, Hb);
  kB<<<dim3(NL, NB), 128, 0, stream>>>(Hb, mask, flag, ra, ca, X2);
  kC<<<NB, 128, 0, stream>>>(Hb, mask, flag, ra, w2, b2, X2, Ab);
  kDm<<<dim3(12, 3), 256, 0, stream>>>(X2, wd, Aj, Ai, Adg);
  kE<<<NROWS/64, 256, 0, stream>>>(Hb, w34t, Aj, Ai, Adg, Ab, out);
}

// Round 5
// 59.907 us; speedup vs baseline: 3.9025x; 1.8821x over previous
//
#include <hip/hip_runtime.h>

typedef __attribute__((ext_vector_type(8))) short short8;
typedef __attribute__((ext_vector_type(4))) float f32x4;
typedef __attribute__((ext_vector_type(4))) unsigned short ushort4_t;

#define NL 48
#define NB 16
#define NROWS (NL*NL*NB)   // 36864

// ---- workspace layout (float units) ----
#define HB_N     (NROWS*128/2)            // bf16 H: 2359296 float-slots
#define HB_OFF   0
#define W1T_OFF  (HB_OFF + HB_N)          // bf16 [128n][128k] = 8192 floats
#define W34T_OFF (W1T_OFF + 8192)         // bf16 [128n][256k] = 16384 floats
#define WD_OFF   (W34T_OFF + 16384)       // bf16 [384n][384k] = 73728 floats
#define X2_OFF   (WD_OFF + 73728)         // bf16 [768m][384k] = 147456 floats
#define VEC_N    (NL*NB*128)              // 98304
#define RA_OFF   (X2_OFF + 147456)
#define AJ_OFF   (RA_OFF + VEC_N)
#define AI_OFF   (AJ_OFF + VEC_N)
#define AD_OFF   (AI_OFF + VEC_N)
#define AB_OFF   (AD_OFF + VEC_N)
#define DGA_OFF  (AB_OFF + NB*128)
#define FLAG_OFF (DGA_OFF + NB*128)

__device__ __forceinline__ float silu_f(float x) { return x / (1.0f + __expf(-x)); }
__device__ __forceinline__ unsigned short f2bf(float x) {
  union { float f; unsigned u; } v; v.f = x;
  unsigned r = v.u + 0x7fffu + ((v.u >> 16) & 1u);
  return (unsigned short)(r >> 16);
}
__device__ __forceinline__ float bf2f(unsigned short h) {
  union { unsigned u; float f; } v; v.u = ((unsigned)h) << 16; return v.f;
}

// ---------- kPrep: weight transposes + Wd pack + mask-dtype detect ----------
// blocks 0-3: w1t; 4-11: w34t; 12-47: wd (384x384); 48: detect
__global__ __launch_bounds__(256) void kPrep(const float* __restrict__ w1,
    const float* __restrict__ w2, const unsigned char* __restrict__ mb,
    unsigned short* __restrict__ w1t, unsigned short* __restrict__ w34t,
    unsigned short* __restrict__ wd, int* __restrict__ flag)
{
  __shared__ float t[64*65];
  __shared__ int any;
  int blk = blockIdx.x, tid = threadIdx.x;
  if (blk < 4) {
    int k0 = (blk & 1)*64, n0 = (blk >> 1)*64;
    #pragma unroll
    for (int it = 0; it < 16; ++it) { int f = it*256+tid; int kk=f>>6, nn=f&63;
      t[kk*65+nn] = w1[(k0+kk)*128 + n0+nn]; }
    __syncthreads();
    #pragma unroll
    for (int it = 0; it < 16; ++it) { int f = it*256+tid; int nn=f>>6, kk=f&63;
      w1t[(n0+nn)*128 + k0+kk] = f2bf(t[kk*65+nn]); }
  } else if (blk < 12) {
    int q = blk-4; int k0 = (q&3)*64, n0 = (q>>2)*64;
    #pragma unroll
    for (int it = 0; it < 16; ++it) { int f = it*256+tid; int kk=f>>6, nn=f&63;
      int k = k0+kk; int slice = (k < 128) ? 4 : 3;
      t[kk*65+nn] = w2[slice*16384 + (k&127)*128 + n0+nn]; }
    __syncthreads();
    #pragma unroll
    for (int it = 0; it < 16; ++it) { int f = it*256+tid; int nn=f>>6, kk=f&63;
      w34t[(n0+nn)*256 + k0+kk] = f2bf(t[kk*65+nn]); }
  } else if (blk < 48) {
    int q = blk-12; int k0 = (q%6)*64, n0 = (q/6)*64;
    int nq = n0 >> 7, kq = k0 >> 7;
    int slice;
    {
      const int sl_aj[3] = {1,9,10};     // d, ra, ca
      const int sl_ai[3] = {2,13,12};
      const int sl_ad[3] = {0,5,6};
      slice = (nq==0) ? sl_aj[kq] : (nq==1) ? sl_ai[kq] : sl_ad[kq];
    }
    int nb = n0 & 127;
    #pragma unroll
    for (int it = 0; it < 16; ++it) { int f = it*256+tid; int kk=f>>6, nn=f&63;
      t[kk*65+nn] = w2[slice*16384 + ((k0&127)+kk)*128 + nb+nn]; }
    __syncthreads();
    #pragma unroll
    for (int it = 0; it < 16; ++it) { int f = it*256+tid; int nn=f>>6, kk=f&63;
      wd[(n0+nn)*384 + k0+kk] = f2bf(t[kk*65+nn]); }
  } else {
    if (tid == 0) any = 0;
    __syncthreads();
    int acc = 0;
    #pragma unroll
    for (int k2 = 0; k2 < 12; ++k2) {
      uchar4 v = ((const uchar4*)mb)[tid + k2*256];
      acc |= v.y | v.z | v.w;
    }
    if (acc) atomicOr(&any, 1);
    __syncthreads();
    if (tid == 0) *flag = any ? 1 : 4;
  }
}

// ---------- kernel A (MFMA): Hb = bf16(silu(BN(T) @ w1 + b1)) ----------
__global__ __launch_bounds__(256) void kA(const float* __restrict__ T,
    const float* __restrict__ rmean, const float* __restrict__ rvar,
    const float* __restrict__ bw, const float* __restrict__ bb,
    const unsigned short* __restrict__ w1t, const float* __restrict__ b1,
    unsigned short* __restrict__ Hb)
{
  __shared__ __align__(16) char XDS[64*256];    // [64 r][128 k] bf16, XOR-swizzled
  __shared__ __align__(16) char WDS[128*256];   // [128 n][128 k] bf16, XOR-swizzled
  int tid = threadIdx.x;
  int m0 = blockIdx.x * 64;

  int cbase = (tid & 31) * 4;
  float scr[4], shr[4];
  #pragma unroll
  for (int u = 0; u < 4; ++u) {
    float s = bw[cbase+u] * rsqrtf(rvar[cbase+u] + 1e-5f);
    scr[u] = s; shr[u] = bb[cbase+u] - rmean[cbase+u] * s;
  }
  #pragma unroll
  for (int t = 0; t < 8; ++t) {
    int f = t*256 + tid;
    int r = f >> 5, c4 = f & 31;
    float4 v = *(const float4*)&T[(m0 + r)*128 + c4*4];
    ushort4_t p;
    p.x = f2bf(v.x*scr[0] + shr[0]); p.y = f2bf(v.y*scr[1] + shr[1]);
    p.z = f2bf(v.z*scr[2] + shr[2]); p.w = f2bf(v.w*scr[3] + shr[3]);
    *(ushort4_t*)(XDS + r*256 + ((c4*8) ^ ((r & 7) << 4))) = p;
  }
  #pragma unroll
  for (int t = 0; t < 8; ++t) {
    int f = t*256 + tid;
    int r = f >> 4, c16 = f & 15;
    short8 v = *(const short8*)(w1t + r*128 + c16*8);
    *(short8*)(WDS + r*256 + ((c16*16) ^ ((r & 7) << 4))) = v;
  }
  __syncthreads();

  int wave = tid >> 6, lane = tid & 63;
  int ln = lane & 15, lg = lane >> 4;
  int rw = (wave >> 1) * 32, cw = (wave & 1) * 64;
  int swz = (ln & 7) << 4;
  f32x4 acc[2][4];
  #pragma unroll
  for (int mt = 0; mt < 2; ++mt)
    #pragma unroll
    for (int nt = 0; nt < 4; ++nt) acc[mt][nt] = (f32x4){0.f,0.f,0.f,0.f};

  #pragma unroll
  for (int ks = 0; ks < 4; ++ks) {
    int kb = ks*64 + lg*16;
    short8 a[2], b[4];
    #pragma unroll
    for (int mt = 0; mt < 2; ++mt)
      a[mt] = *(const short8*)(XDS + (rw + mt*16 + ln)*256 + (kb ^ swz));
    #pragma unroll
    for (int nt = 0; nt < 4; ++nt)
      b[nt] = *(const short8*)(WDS + (cw + nt*16 + ln)*256 + (kb ^ swz));
    #pragma unroll
    for (int mt = 0; mt < 2; ++mt)
      #pragma unroll
      for (int nt = 0; nt < 4; ++nt)
        acc[mt][nt] = __builtin_amdgcn_mfma_f32_16x16x32_bf16(a[mt], b[nt], acc[mt][nt], 0, 0, 0);
  }
  float b1v[4];
  #pragma unroll
  for (int nt = 0; nt < 4; ++nt) b1v[nt] = b1[cw + nt*16 + ln];
  #pragma unroll
  for (int mt = 0; mt < 2; ++mt)
    #pragma unroll
    for (int q = 0; q < 4; ++q) {
      int m = m0 + rw + mt*16 + 4*lg + q;
      #pragma unroll
      for (int nt = 0; nt < 4; ++nt) {
        float x = acc[mt][nt][q] + b1v[nt];
        Hb[m*128 + cw + nt*16 + ln] = f2bf(silu_f(x));
      }
    }
}

// ---------- kAgg: branch-free masked row/col sums + X2 chunks 0-2 ----------
// 128 threads: half 0 = col_agg (sum over axis1) + diag copy; half 1 = row_agg.
__global__ __launch_bounds__(128) void kAgg(const unsigned short* __restrict__ Hb,
    const unsigned char* __restrict__ mb, const int* __restrict__ flag,
    float* __restrict__ ra, unsigned short* __restrict__ X2)
{
  int p = blockIdx.x, b = blockIdx.y;
  int tid = threadIdx.x;
  int s = *flag;
  int half = tid >> 6;
  int t = tid & 63;            // e-pair: e = 2t, 2t+1
  float a0 = 0.f, a1 = 0.f;
  #pragma unroll 16
  for (int q = 0; q < NL; ++q) {
    int mi = half ? ((q*NL + p)*NB + b) : ((p*NL + q)*NB + b);
    float mv = (float)mb[mi*s];
    unsigned u = *(const unsigned*)(Hb + mi*128 + 2*t);
    a0 += mv * bf2f((unsigned short)(u & 0xffffu));
    a1 += mv * bf2f((unsigned short)(u >> 16));
  }
  a0 *= (1.0f/60.0f); a1 *= (1.0f/60.0f);
  int ix = p*NB + b;
  unsigned pk = ((unsigned)f2bf(a1) << 16) | (unsigned)f2bf(a0);
  if (half) {  // row_agg -> ra buffer + X2 chunk1
    *(float2*)(ra + ix*128 + 2*t) = make_float2(a0, a1);
    *(unsigned*)(X2 + ix*384 + 128 + 2*t) = pk;
  } else {     // col_agg -> X2 chunk2; diag -> X2 chunk0
    *(unsigned*)(X2 + ix*384 + 256 + 2*t) = pk;
    unsigned d = *(const unsigned*)(Hb + ((p*NL + p)*NB + b)*128 + 2*t);
    *(unsigned*)(X2 + ix*384 + 2*t) = d;
  }
}

// ---------- kDm: y<3 MFMA [Aj|Ai|Adg] = X2 @ Wd^T ; y==3: Abase/Dga per b ----------
__global__ __launch_bounds__(256) void kDm(const unsigned short* __restrict__ X2,
    const unsigned short* __restrict__ wd,
    const unsigned short* __restrict__ Hb, const unsigned char* __restrict__ mb,
    const int* __restrict__ flag, const float* __restrict__ ra,
    const float* __restrict__ w2, const float* __restrict__ b2,
    float* __restrict__ Aj, float* __restrict__ Ai, float* __restrict__ Adg,
    float* __restrict__ Ab, float* __restrict__ Dga)
{
  int tid = threadIdx.x;
  if (blockIdx.y == 3) {
    int b = blockIdx.x;   // 0..15
    __shared__ float aas[128], dgs[128];
    int e = tid & 127;
    if (tid < 128) {
      int s = *flag;
      float aa = 0.f, dg = 0.f;
      #pragma unroll 8
      for (int p = 0; p < NL; ++p) {
        aa += ra[(p*NB + b)*128 + e];
        int mi = (p*NL + p)*NB + b;
        dg += (float)mb[mi*s] * bf2f(Hb[mi*128 + e]);
      }
      aas[e] = aa * (1.0f/60.0f);
      dgs[e] = dg * (1.0f/60.0f);
    }
    __syncthreads();
    if (tid < 128) {
      float ab = b2[e];
      #pragma unroll 8
      for (int k = 0; k < 128; ++k) {
        int o = k*128 + e;
        ab += dgs[k]*w2[8*16384 + o] + aas[k]*(w2[11*16384 + o] + w2[14*16384 + o]);
      }
      Ab[b*128 + e] = ab;
    } else {
      float dga = 0.f;
      #pragma unroll 8
      for (int k = 0; k < 128; ++k)
        dga += dgs[k]*w2[7*16384 + k*128 + e];
      Dga[b*128 + e] = dga;
    }
    return;
  }
  if (blockIdx.x >= 12) return;

  __shared__ __align__(16) char ADS[64*256];
  __shared__ __align__(16) char BDS[128*256];
  int m0 = blockIdx.x * 64;
  int n0 = blockIdx.y * 128;

  int wave = tid >> 6, lane = tid & 63;
  int ln = lane & 15, lg = lane >> 4;
  int rw = (wave >> 1) * 32, cw = (wave & 1) * 64;
  int swzk = (ln & 7) << 4;
  f32x4 acc[2][4];
  #pragma unroll
  for (int mt = 0; mt < 2; ++mt)
    #pragma unroll
    for (int nt = 0; nt < 4; ++nt) acc[mt][nt] = (f32x4){0.f,0.f,0.f,0.f};

  for (int kc = 0; kc < 3; ++kc) {
    if (kc) __syncthreads();
    #pragma unroll
    for (int t = 0; t < 4; ++t) {
      int f = t*256 + tid;
      int r = f >> 4, c16 = f & 15;
      short8 v = *(const short8*)(X2 + (m0 + r)*384 + kc*128 + c16*8);
      *(short8*)(ADS + r*256 + ((c16*16) ^ ((r & 7) << 4))) = v;
    }
    #pragma unroll
    for (int t = 0; t < 8; ++t) {
      int f = t*256 + tid;
      int r = f >> 4, c16 = f & 15;
      short8 v = *(const short8*)(wd + (n0 + r)*384 + kc*128 + c16*8);
      *(short8*)(BDS + r*256 + ((c16*16) ^ ((r & 7) << 4))) = v;
    }
    __syncthreads();
    #pragma unroll
    for (int ks = 0; ks < 4; ++ks) {
      int kb = ks*64 + lg*16;
      short8 a[2], b[4];
      #pragma unroll
      for (int mt = 0; mt < 2; ++mt)
        a[mt] = *(const short8*)(ADS + (rw + mt*16 + ln)*256 + (kb ^ swzk));
      #pragma unroll
      for (int nt = 0; nt < 4; ++nt)
        b[nt] = *(const short8*)(BDS + (cw + nt*16 + ln)*256 + (kb ^ swzk));
      #pragma unroll
      for (int mt = 0; mt < 2; ++mt)
        #pragma unroll
        for (int nt = 0; nt < 4; ++nt)
          acc[mt][nt] = __builtin_amdgcn_mfma_f32_16x16x32_bf16(a[mt], b[nt], acc[mt][nt], 0, 0, 0);
    }
  }
  float* outp = (blockIdx.y == 0) ? Aj : (blockIdx.y == 1) ? Ai : Adg;
  #pragma unroll
  for (int mt = 0; mt < 2; ++mt)
    #pragma unroll
    for (int q = 0; q < 4; ++q) {
      int row = m0 + rw + mt*16 + 4*lg + q;
      #pragma unroll
      for (int nt = 0; nt < 4; ++nt)
        outp[row*128 + cw + nt*16 + ln] = acc[mt][nt][q];
    }
}

// ---------- kernel E (MFMA): out = [Hd|Ht] @ W34T^T + additive ----------
__global__ __launch_bounds__(256) void kE(const unsigned short* __restrict__ Hb,
    const unsigned short* __restrict__ w34t,
    const float* __restrict__ Aj, const float* __restrict__ Ai,
    const float* __restrict__ Adg, const float* __restrict__ Ab,
    const float* __restrict__ Dga,
    float* __restrict__ out)
{
  __shared__ __align__(16) char ADS[64*512];
  __shared__ __align__(16) char BDS[128*256];
  int tid = threadIdx.x;
  int bi = blockIdx.x / 12;
  int j0 = (blockIdx.x % 12) * 4;

  #pragma unroll
  for (int t = 0; t < 8; ++t) {
    int f = t*256 + tid;
    int r = f >> 5, c16 = f & 31;
    int j = j0 + (r >> 4), b = r & 15;
    int srcrow = (c16 < 16) ? ((bi*NL + j)*NB + b) : ((j*NL + bi)*NB + b);
    short8 v = *(const short8*)(Hb + srcrow*128 + (c16 & 15)*8);
    *(short8*)(ADS + r*512 + ((c16*16) ^ ((r & 7) << 4))) = v;
  }

  int wave = tid >> 6, lane = tid & 63;
  int ln = lane & 15, lg = lane >> 4;
  int rw = (wave >> 1) * 32, cw = (wave & 1) * 64;
  int swz = (ln & 7) << 4;
  f32x4 acc[2][4];
  #pragma unroll
  for (int mt = 0; mt < 2; ++mt)
    #pragma unroll
    for (int nt = 0; nt < 4; ++nt) acc[mt][nt] = (f32x4){0.f,0.f,0.f,0.f};

  #pragma unroll
  for (int half = 0; half < 2; ++half) {
    __syncthreads();
    #pragma unroll
    for (int t = 0; t < 8; ++t) {
      int f = t*256 + tid;
      int r = f >> 4, c16 = f & 15;
      short8 v = *(const short8*)(w34t + r*256 + half*128 + c16*8);
      *(short8*)(BDS + r*256 + ((c16*16) ^ ((r & 7) << 4))) = v;
    }
    __syncthreads();
    #pragma unroll
    for (int ks = 0; ks < 4; ++ks) {
      int kbA = half*256 + ks*64 + lg*16;
      int kbB = ks*64 + lg*16;
      short8 a[2], b[4];
      #pragma unroll
      for (int mt = 0; mt < 2; ++mt)
        a[mt] = *(const short8*)(ADS + (rw + mt*16 + ln)*512 + (kbA ^ swz));
      #pragma unroll
      for (int nt = 0; nt < 4; ++nt)
        b[nt] = *(const short8*)(BDS + (cw + nt*16 + ln)*256 + (kbB ^ swz));
      #pragma unroll
      for (int mt = 0; mt < 2; ++mt)
        #pragma unroll
        for (int nt = 0; nt < 4; ++nt)
          acc[mt][nt] = __builtin_amdgcn_mfma_f32_16x16x32_bf16(a[mt], b[nt], acc[mt][nt], 0, 0, 0);
    }
  }

  #pragma unroll
  for (int mt = 0; mt < 2; ++mt) {
    int tb = rw + mt*16;
    int jj = tb >> 4;
    int j = j0 + jj;
    bool isdiag = (bi == j);
    #pragma unroll
    for (int q = 0; q < 4; ++q) {
      int b = 4*lg + q;
      int m = (bi*NL + j)*NB + b;
      #pragma unroll
      for (int nt = 0; nt < 4; ++nt) {
        int n = cw + nt*16 + ln;
        float add = Aj[(j*NB + b)*128 + n] + Ai[(bi*NB + b)*128 + n] + Ab[b*128 + n];
        if (isdiag) add += Adg[(bi*NB + b)*128 + n] + Dga[b*128 + n];
        out[m*128 + n] = acc[mt][nt][q] + add;
      }
    }
  }
}

extern "C" void kernel_launch(void* const* d_in, const int* in_sizes, int n_in,
                              void* d_out, int out_size, void* d_ws, size_t ws_size,
                              hipStream_t stream) {
  (void)in_sizes; (void)n_in; (void)out_size; (void)ws_size;
  const float* T      = (const float*)d_in[0];
  const unsigned char* mask = (const unsigned char*)d_in[1];
  const float* rmean  = (const float*)d_in[2];
  const float* rvar   = (const float*)d_in[3];
  const float* bw     = (const float*)d_in[4];
  const float* bb     = (const float*)d_in[5];
  const float* w1     = (const float*)d_in[6];
  const float* b1     = (const float*)d_in[7];
  const float* w2     = (const float*)d_in[8];
  const float* b2     = (const float*)d_in[9];
  float* ws  = (float*)d_ws;
  float* out = (float*)d_out;

  unsigned short* Hb   = (unsigned short*)(ws + HB_OFF);
  unsigned short* w1t  = (unsigned short*)(ws + W1T_OFF);
  unsigned short* w34t = (unsigned short*)(ws + W34T_OFF);
  unsigned short* wd   = (unsigned short*)(ws + WD_OFF);
  unsigned short* X2   = (unsigned short*)(ws + X2_OFF);
  float* ra   = ws + RA_OFF;
  float* Aj   = ws + AJ_OFF;
  float* Ai   = ws + AI_OFF;
  float* Adg  = ws + AD_OFF;
  float* Ab   = ws + AB_OFF;
  float* Dga  = ws + DGA_OFF;
  int*   flag = (int*)(ws + FLAG_OFF);

  kPrep<<<49, 256, 0, stream>>>(w1, w2, mask, w1t, w34t, wd, flag);
  kA<<<NROWS/64, 256, 0, stream>>>(T, rmean, rvar, bw, bb, w1t, b1, Hb);
  kAgg<<<dim3(NL, NB), 128, 0, stream>>>(Hb, mask, flag, ra, X2);
  kDm<<<dim3(16, 4), 256, 0, stream>>>(X2, wd, Hb, mask, flag, ra, w2, b2, Aj, Ai, Adg, Ab, Dga);
  kE<<<NROWS/64, 256, 0, stream>>>(Hb, w34t, Aj, Ai, Adg, Ab, Dga, out);
}

// Round 6
// 50.418 us; speedup vs baseline: 4.6369x; 1.1882x over previous
//
#include <hip/hip_runtime.h>

typedef __attribute__((ext_vector_type(8))) short short8;
typedef __attribute__((ext_vector_type(4))) float f32x4;
typedef __attribute__((ext_vector_type(4))) unsigned short ushort4_t;

#define NL 48
#define NB 16
#define NROWS (NL*NL*NB)   // 36864

// ---- workspace layout (float units) ----
#define HB_N     (NROWS*128/2)            // bf16 H: 2359296 float-slots
#define HB_OFF   0
#define W34T_OFF (HB_OFF + HB_N)          // bf16 [128n][256k] = 16384 floats
#define WD_OFF   (W34T_OFF + 16384)       // bf16 [384n][384k] = 73728 floats
#define X2_OFF   (WD_OFF + 73728)         // bf16 [768m][384k] = 147456 floats
#define VEC_N    (NL*NB*128)              // 98304
#define RA_OFF   (X2_OFF + 147456)
#define AJ_OFF   (RA_OFF + VEC_N)
#define AI_OFF   (AJ_OFF + VEC_N)
#define AD_OFF   (AI_OFF + VEC_N)
#define AB_OFF   (AD_OFF + VEC_N)
#define DGA_OFF  (AB_OFF + NB*128)
#define FLAG_OFF (DGA_OFF + NB*128)

__device__ __forceinline__ float silu_f(float x) { return x / (1.0f + __expf(-x)); }
__device__ __forceinline__ unsigned short f2bf(float x) {
  union { float f; unsigned u; } v; v.f = x;
  unsigned r = v.u + 0x7fffu + ((v.u >> 16) & 1u);
  return (unsigned short)(r >> 16);
}
__device__ __forceinline__ float bf2f(unsigned short h) {
  union { unsigned u; float f; } v; v.u = ((unsigned)h) << 16; return v.f;
}

// ---------- kernel A (MFMA) + embedded prep ----------
// blocks 0..575: Hb = bf16(silu(BN(T) @ w1 + b1))   (w1 transposed in-block)
// blocks 576..583: w34t ; 584..619: wd ; 620: mask-dtype detect
__global__ __launch_bounds__(256) void kA(const float* __restrict__ T,
    const float* __restrict__ rmean, const float* __restrict__ rvar,
    const float* __restrict__ bw, const float* __restrict__ bb,
    const float* __restrict__ w1, const float* __restrict__ b1,
    const float* __restrict__ w2, const unsigned char* __restrict__ mb,
    unsigned short* __restrict__ Hb, unsigned short* __restrict__ w34t,
    unsigned short* __restrict__ wd, int* __restrict__ flag)
{
  __shared__ __align__(16) char SM[49152];
  __shared__ int any;
  char* XDS = SM;            // [64 r][128 k] bf16 swizzled (16 KB)
  char* WDS = SM + 16384;    // [128 n][128 k] bf16 swizzled (32 KB)
  float* tt = (float*)SM;    // prep transpose tile (prep blocks only)
  int tid = threadIdx.x;
  int blk = blockIdx.x;

  if (blk >= 576) {
    int pb = blk - 576;
    if (pb < 8) {            // w34t[n][k]: k<128 -> w2 slice4, k>=128 -> slice3
      int k0 = (pb & 3)*64, n0 = (pb >> 2)*64;
      #pragma unroll
      for (int it = 0; it < 16; ++it) { int f = it*256+tid; int kk=f>>6, nn=f&63;
        int k = k0+kk; int slice = (k < 128) ? 4 : 3;
        tt[kk*65+nn] = w2[slice*16384 + (k&127)*128 + n0+nn]; }
      __syncthreads();
      #pragma unroll
      for (int it = 0; it < 16; ++it) { int f = it*256+tid; int nn=f>>6, kk=f&63;
        w34t[(n0+nn)*256 + k0+kk] = f2bf(tt[kk*65+nn]); }
    } else if (pb < 44) {    // wd [384n][384k]
      int q = pb-8; int k0 = (q%6)*64, n0 = (q/6)*64;
      int nq = n0 >> 7, kq = k0 >> 7;
      int slice;
      {
        const int sl_aj[3] = {1,9,10};
        const int sl_ai[3] = {2,13,12};
        const int sl_ad[3] = {0,5,6};
        slice = (nq==0) ? sl_aj[kq] : (nq==1) ? sl_ai[kq] : sl_ad[kq];
      }
      int nb = n0 & 127;
      #pragma unroll
      for (int it = 0; it < 16; ++it) { int f = it*256+tid; int kk=f>>6, nn=f&63;
        tt[kk*65+nn] = w2[slice*16384 + ((k0&127)+kk)*128 + nb+nn]; }
      __syncthreads();
      #pragma unroll
      for (int it = 0; it < 16; ++it) { int f = it*256+tid; int nn=f>>6, kk=f&63;
        wd[(n0+nn)*384 + k0+kk] = f2bf(tt[kk*65+nn]); }
    } else {                 // detect mask byte-stride
      if (tid == 0) any = 0;
      __syncthreads();
      int acc = 0;
      #pragma unroll
      for (int k2 = 0; k2 < 12; ++k2) {
        uchar4 v = ((const uchar4*)mb)[tid + k2*256];
        acc |= v.y | v.z | v.w;
      }
      if (acc) atomicOr(&any, 1);
      __syncthreads();
      if (tid == 0) *flag = any ? 1 : 4;
    }
    return;
  }

  int m0 = blk * 64;
  // per-thread BN constants for its 4 fixed columns
  int cbase = (tid & 31) * 4;
  float scr[4], shr[4];
  #pragma unroll
  for (int u = 0; u < 4; ++u) {
    float s = bw[cbase+u] * rsqrtf(rvar[cbase+u] + 1e-5f);
    scr[u] = s; shr[u] = bb[cbase+u] - rmean[cbase+u] * s;
  }
  // stage X (BN + bf16)
  #pragma unroll
  for (int t = 0; t < 8; ++t) {
    int f = t*256 + tid;
    int r = f >> 5, c4 = f & 31;
    float4 v = *(const float4*)&T[(m0 + r)*128 + c4*4];
    ushort4_t p;
    p.x = f2bf(v.x*scr[0] + shr[0]); p.y = f2bf(v.y*scr[1] + shr[1]);
    p.z = f2bf(v.z*scr[2] + shr[2]); p.w = f2bf(v.w*scr[3] + shr[3]);
    *(ushort4_t*)(XDS + r*256 + ((c4*8) ^ ((r & 7) << 4))) = p;
  }
  // stage W1^T: WDS[n][k] from w1[k][n] (strided scalar reads, swizzled b128 writes)
  {
    int n = tid & 127, ch = (tid >> 7) * 8;
    #pragma unroll
    for (int cc = 0; cc < 8; ++cc) {
      int c = ch + cc;
      short8 v;
      #pragma unroll
      for (int j = 0; j < 8; ++j)
        ((unsigned short*)&v)[j] = f2bf(w1[(c*8 + j)*128 + n]);
      *(short8*)(WDS + n*256 + ((c*16) ^ ((n & 7) << 4))) = v;
    }
  }
  __syncthreads();

  int wave = tid >> 6, lane = tid & 63;
  int ln = lane & 15, lg = lane >> 4;
  int rw = (wave >> 1) * 32, cw = (wave & 1) * 64;
  int swz = (ln & 7) << 4;
  f32x4 acc[2][4];
  #pragma unroll
  for (int mt = 0; mt < 2; ++mt)
    #pragma unroll
    for (int nt = 0; nt < 4; ++nt) acc[mt][nt] = (f32x4){0.f,0.f,0.f,0.f};

  #pragma unroll
  for (int ks = 0; ks < 4; ++ks) {
    int kb = ks*64 + lg*16;
    short8 a[2], b[4];
    #pragma unroll
    for (int mt = 0; mt < 2; ++mt)
      a[mt] = *(const short8*)(XDS + (rw + mt*16 + ln)*256 + (kb ^ swz));
    #pragma unroll
    for (int nt = 0; nt < 4; ++nt)
      b[nt] = *(const short8*)(WDS + (cw + nt*16 + ln)*256 + (kb ^ swz));
    #pragma unroll
    for (int mt = 0; mt < 2; ++mt)
      #pragma unroll
      for (int nt = 0; nt < 4; ++nt)
        acc[mt][nt] = __builtin_amdgcn_mfma_f32_16x16x32_bf16(a[mt], b[nt], acc[mt][nt], 0, 0, 0);
  }
  float b1v[4];
  #pragma unroll
  for (int nt = 0; nt < 4; ++nt) b1v[nt] = b1[cw + nt*16 + ln];
  #pragma unroll
  for (int mt = 0; mt < 2; ++mt)
    #pragma unroll
    for (int q = 0; q < 4; ++q) {
      int m = m0 + rw + mt*16 + 4*lg + q;
      #pragma unroll
      for (int nt = 0; nt < 4; ++nt) {
        float x = acc[mt][nt][q] + b1v[nt];
        Hb[m*128 + cw + nt*16 + ln] = f2bf(silu_f(x));
      }
    }
}

// ---------- kAgg: branch-free masked row/col sums + X2 chunks 0-2 ----------
__global__ __launch_bounds__(128) void kAgg(const unsigned short* __restrict__ Hb,
    const unsigned char* __restrict__ mb, const int* __restrict__ flag,
    float* __restrict__ ra, unsigned short* __restrict__ X2)
{
  int p = blockIdx.x, b = blockIdx.y;
  int tid = threadIdx.x;
  int s = *flag;
  int half = tid >> 6;
  int t = tid & 63;
  float a0 = 0.f, a1 = 0.f;
  #pragma unroll 16
  for (int q = 0; q < NL; ++q) {
    int mi = half ? ((q*NL + p)*NB + b) : ((p*NL + q)*NB + b);
    float mv = (float)mb[mi*s];
    unsigned u = *(const unsigned*)(Hb + mi*128 + 2*t);
    a0 += mv * bf2f((unsigned short)(u & 0xffffu));
    a1 += mv * bf2f((unsigned short)(u >> 16));
  }
  a0 *= (1.0f/60.0f); a1 *= (1.0f/60.0f);
  int ix = p*NB + b;
  unsigned pk = ((unsigned)f2bf(a1) << 16) | (unsigned)f2bf(a0);
  if (half) {
    *(float2*)(ra + ix*128 + 2*t) = make_float2(a0, a1);
    *(unsigned*)(X2 + ix*384 + 128 + 2*t) = pk;
  } else {
    *(unsigned*)(X2 + ix*384 + 256 + 2*t) = pk;
    unsigned d = *(const unsigned*)(Hb + ((p*NL + p)*NB + b)*128 + 2*t);
    *(unsigned*)(X2 + ix*384 + 2*t) = d;
  }
}

// ---------- kDm: y<3 MFMA [Aj|Ai|Adg] = X2 @ Wd^T ; y==3: Abase/Dga ----------
__global__ __launch_bounds__(256) void kDm(const unsigned short* __restrict__ X2,
    const unsigned short* __restrict__ wd,
    const unsigned short* __restrict__ Hb, const unsigned char* __restrict__ mb,
    const int* __restrict__ flag, const float* __restrict__ ra,
    const float* __restrict__ w2, const float* __restrict__ b2,
    float* __restrict__ Aj, float* __restrict__ Ai, float* __restrict__ Adg,
    float* __restrict__ Ab, float* __restrict__ Dga)
{
  int tid = threadIdx.x;
  if (blockIdx.y == 3) {
    int b = blockIdx.x;
    __shared__ float aas[128], dgs[128];
    int e = tid & 127;
    if (tid < 128) {
      int s = *flag;
      float aa = 0.f, dg = 0.f;
      #pragma unroll 8
      for (int p = 0; p < NL; ++p) {
        aa += ra[(p*NB + b)*128 + e];
        int mi = (p*NL + p)*NB + b;
        dg += (float)mb[mi*s] * bf2f(Hb[mi*128 + e]);
      }
      aas[e] = aa * (1.0f/60.0f);
      dgs[e] = dg * (1.0f/60.0f);
    }
    __syncthreads();
    if (tid < 128) {
      float ab = b2[e];
      #pragma unroll 8
      for (int k = 0; k < 128; ++k) {
        int o = k*128 + e;
        ab += dgs[k]*w2[8*16384 + o] + aas[k]*(w2[11*16384 + o] + w2[14*16384 + o]);
      }
      Ab[b*128 + e] = ab;
    } else {
      float dga = 0.f;
      #pragma unroll 8
      for (int k = 0; k < 128; ++k)
        dga += dgs[k]*w2[7*16384 + k*128 + e];
      Dga[b*128 + e] = dga;
    }
    return;
  }
  if (blockIdx.x >= 12) return;

  __shared__ __align__(16) char ADS[64*256];
  __shared__ __align__(16) char BDS[128*256];
  int m0 = blockIdx.x * 64;
  int n0 = blockIdx.y * 128;

  int wave = tid >> 6, lane = tid & 63;
  int ln = lane & 15, lg = lane >> 4;
  int rw = (wave >> 1) * 32, cw = (wave & 1) * 64;
  int swzk = (ln & 7) << 4;
  f32x4 acc[2][4];
  #pragma unroll
  for (int mt = 0; mt < 2; ++mt)
    #pragma unroll
    for (int nt = 0; nt < 4; ++nt) acc[mt][nt] = (f32x4){0.f,0.f,0.f,0.f};

  for (int kc = 0; kc < 3; ++kc) {
    if (kc) __syncthreads();
    #pragma unroll
    for (int t = 0; t < 4; ++t) {
      int f = t*256 + tid;
      int r = f >> 4, c16 = f & 15;
      short8 v = *(const short8*)(X2 + (m0 + r)*384 + kc*128 + c16*8);
      *(short8*)(ADS + r*256 + ((c16*16) ^ ((r & 7) << 4))) = v;
    }
    #pragma unroll
    for (int t = 0; t < 8; ++t) {
      int f = t*256 + tid;
      int r = f >> 4, c16 = f & 15;
      short8 v = *(const short8*)(wd + (n0 + r)*384 + kc*128 + c16*8);
      *(short8*)(BDS + r*256 + ((c16*16) ^ ((r & 7) << 4))) = v;
    }
    __syncthreads();
    #pragma unroll
    for (int ks = 0; ks < 4; ++ks) {
      int kb = ks*64 + lg*16;
      short8 a[2], b[4];
      #pragma unroll
      for (int mt = 0; mt < 2; ++mt)
        a[mt] = *(const short8*)(ADS + (rw + mt*16 + ln)*256 + (kb ^ swzk));
      #pragma unroll
      for (int nt = 0; nt < 4; ++nt)
        b[nt] = *(const short8*)(BDS + (cw + nt*16 + ln)*256 + (kb ^ swzk));
      #pragma unroll
      for (int mt = 0; mt < 2; ++mt)
        #pragma unroll
        for (int nt = 0; nt < 4; ++nt)
          acc[mt][nt] = __builtin_amdgcn_mfma_f32_16x16x32_bf16(a[mt], b[nt], acc[mt][nt], 0, 0, 0);
    }
  }
  float* outp = (blockIdx.y == 0) ? Aj : (blockIdx.y == 1) ? Ai : Adg;
  #pragma unroll
  for (int mt = 0; mt < 2; ++mt)
    #pragma unroll
    for (int q = 0; q < 4; ++q) {
      int row = m0 + rw + mt*16 + 4*lg + q;
      #pragma unroll
      for (int nt = 0; nt < 4; ++nt)
        outp[row*128 + cw + nt*16 + ln] = acc[mt][nt][q];
    }
}

// ---------- kernel E (MFMA): out = Hd@W4 + Ht@W3 + additive ----------
// A restaged per K-half (16 KB) + BDS per half (32 KB) -> 48 KB LDS, 3 blocks/CU
__global__ __launch_bounds__(256) void kE(const unsigned short* __restrict__ Hb,
    const unsigned short* __restrict__ w34t,
    const float* __restrict__ Aj, const float* __restrict__ Ai,
    const float* __restrict__ Adg, const float* __restrict__ Ab,
    const float* __restrict__ Dga,
    float* __restrict__ out)
{
  __shared__ __align__(16) char ADS[64*256];
  __shared__ __align__(16) char BDS[128*256];
  int tid = threadIdx.x;
  int bi = blockIdx.x / 12;
  int j0 = (blockIdx.x % 12) * 4;
  int m0 = (bi*NL + j0) * NB;

  int wave = tid >> 6, lane = tid & 63;
  int ln = lane & 15, lg = lane >> 4;
  int rw = (wave >> 1) * 32, cw = (wave & 1) * 64;
  int swz = (ln & 7) << 4;
  f32x4 acc[2][4];
  #pragma unroll
  for (int mt = 0; mt < 2; ++mt)
    #pragma unroll
    for (int nt = 0; nt < 4; ++nt) acc[mt][nt] = (f32x4){0.f,0.f,0.f,0.f};

  #pragma unroll
  for (int half = 0; half < 2; ++half) {
    if (half) __syncthreads();     // protect buffer reuse
    // stage A half: half0 = Hd rows (contiguous), half1 = Ht rows
    #pragma unroll
    for (int t = 0; t < 4; ++t) {
      int f = t*256 + tid;
      int r = f >> 4, c16 = f & 15;
      int srcrow = (half == 0) ? (m0 + r) : ((j0 + (r >> 4))*NL + bi)*NB + (r & 15);
      short8 v = *(const short8*)(Hb + srcrow*128 + c16*8);
      *(short8*)(ADS + r*256 + ((c16*16) ^ ((r & 7) << 4))) = v;
    }
    // stage B half
    #pragma unroll
    for (int t = 0; t < 8; ++t) {
      int f = t*256 + tid;
      int r = f >> 4, c16 = f & 15;
      short8 v = *(const short8*)(w34t + r*256 + half*128 + c16*8);
      *(short8*)(BDS + r*256 + ((c16*16) ^ ((r & 7) << 4))) = v;
    }
    __syncthreads();
    #pragma unroll
    for (int ks = 0; ks < 4; ++ks) {
      int kb = ks*64 + lg*16;
      short8 a[2], b[4];
      #pragma unroll
      for (int mt = 0; mt < 2; ++mt)
        a[mt] = *(const short8*)(ADS + (rw + mt*16 + ln)*256 + (kb ^ swz));
      #pragma unroll
      for (int nt = 0; nt < 4; ++nt)
        b[nt] = *(const short8*)(BDS + (cw + nt*16 + ln)*256 + (kb ^ swz));
      #pragma unroll
      for (int mt = 0; mt < 2; ++mt)
        #pragma unroll
        for (int nt = 0; nt < 4; ++nt)
          acc[mt][nt] = __builtin_amdgcn_mfma_f32_16x16x32_bf16(a[mt], b[nt], acc[mt][nt], 0, 0, 0);
    }
  }

  #pragma unroll
  for (int mt = 0; mt < 2; ++mt) {
    int tb = rw + mt*16;
    int jj = tb >> 4;
    int j = j0 + jj;
    bool isdiag = (bi == j);
    #pragma unroll
    for (int q = 0; q < 4; ++q) {
      int b = 4*lg + q;
      int m = (bi*NL + j)*NB + b;
      #pragma unroll
      for (int nt = 0; nt < 4; ++nt) {
        int n = cw + nt*16 + ln;
        float add = Aj[(j*NB + b)*128 + n] + Ai[(bi*NB + b)*128 + n] + Ab[b*128 + n];
        if (isdiag) add += Adg[(bi*NB + b)*128 + n] + Dga[b*128 + n];
        out[m*128 + n] = acc[mt][nt][q] + add;
      }
    }
  }
}

extern "C" void kernel_launch(void* const* d_in, const int* in_sizes, int n_in,
                              void* d_out, int out_size, void* d_ws, size_t ws_size,
                              hipStream_t stream) {
  (void)in_sizes; (void)n_in; (void)out_size; (void)ws_size;
  const float* T      = (const float*)d_in[0];
  const unsigned char* mask = (const unsigned char*)d_in[1];
  const float* rmean  = (const float*)d_in[2];
  const float* rvar   = (const float*)d_in[3];
  const float* bw     = (const float*)d_in[4];
  const float* bb     = (const float*)d_in[5];
  const float* w1     = (const float*)d_in[6];
  const float* b1     = (const float*)d_in[7];
  const float* w2     = (const float*)d_in[8];
  const float* b2     = (const float*)d_in[9];
  float* ws  = (float*)d_ws;
  float* out = (float*)d_out;

  unsigned short* Hb   = (unsigned short*)(ws + HB_OFF);
  unsigned short* w34t = (unsigned short*)(ws + W34T_OFF);
  unsigned short* wd   = (unsigned short*)(ws + WD_OFF);
  unsigned short* X2   = (unsigned short*)(ws + X2_OFF);
  float* ra   = ws + RA_OFF;
  float* Aj   = ws + AJ_OFF;
  float* Ai   = ws + AI_OFF;
  float* Adg  = ws + AD_OFF;
  float* Ab   = ws + AB_OFF;
  float* Dga  = ws + DGA_OFF;
  int*   flag = (int*)(ws + FLAG_OFF);

  kA<<<621, 256, 0, stream>>>(T, rmean, rvar, bw, bb, w1, b1, w2, mask,
                              Hb, w34t, wd, flag);
  kAgg<<<dim3(NL, NB), 128, 0, stream>>>(Hb, mask, flag, ra, X2);
  kDm<<<dim3(16, 4), 256, 0, stream>>>(X2, wd, Hb, mask, flag, ra, w2, b2,
                                       Aj, Ai, Adg, Ab, Dga);
  kE<<<NROWS/64, 256, 0, stream>>>(Hb, w34t, Aj, Ai, Adg, Ab, Dga, out);
}